// Round 6
// baseline (273.344 us; speedup 1.0000x reference)
//
#include <hip/hip_runtime.h>

// GAT attention weights (heads=1) for two block-diagonal graphs.
// Output = softmax-by-dst of leakyrelu(a_s[src]+a_d[dst]) over N*N edges.
//
// R6: explicit register software-pipelining (A/B batches of 2 iterations)
// in both edge kernels. R5 evidence: VGPR_Count=16 -> each wave had ~1
// outstanding load; with 512 blocks all co-resident, wall time = 8 iters x
// ~29K cyc of queued-memory latency. Fix MLP, keep VGPR <= ~64 so 8
// waves/SIMD (2 blocks/CU) survive — R3 showed occupancy collapse kills.
//
//  k3: a_s[src] via LDS, a_d[dst] via global/L1, LDS-atomic accumulate,
//      stream ex to d_out. k5: stream ex back + inv_denom[dst] via LDS,
//      in-place scale. No segment-max: logits bounded -> exp safe in fp32.

#define NNODES 4096
#define NSEG   8192
#define NEG_SLOPE 0.2f
#define EK_TPB 1024
#define EK_QPB 8192          // int4 quads per edge-kernel block = 32768 edges

__global__ void k1_wvec(const float* __restrict__ W,
                        const float* __restrict__ att_src,
                        const float* __restrict__ att_dst,
                        float* __restrict__ wvs, float* __restrict__ wvd) {
    int f = threadIdx.x;
    const float* row = W + f * 128;
    float s = 0.f, d = 0.f;
    #pragma unroll 8
    for (int j = 0; j < 128; ++j) {
        float w = row[j];
        s += w * att_src[j];
        d += w * att_dst[j];
    }
    wvs[f] = s; wvd[f] = d;
}

__global__ void k2_logits(const float* __restrict__ x1, const float* __restrict__ x2,
                          const float* __restrict__ wvs, const float* __restrict__ wvd,
                          float* __restrict__ a_s, float* __restrict__ a_d) {
    int wave = blockIdx.x * 4 + (threadIdx.x >> 6);
    int lane = threadIdx.x & 63;
    const float* xrow = (wave < NNODES) ? (x1 + (size_t)wave * 256)
                                        : (x2 + (size_t)(wave - NNODES) * 256);
    float4 xv  = ((const float4*)xrow)[lane];
    float4 wsv = ((const float4*)wvs)[lane];
    float4 wdv = ((const float4*)wvd)[lane];
    float ps = xv.x*wsv.x + xv.y*wsv.y + xv.z*wsv.z + xv.w*wsv.w;
    float pd = xv.x*wdv.x + xv.y*wdv.y + xv.z*wdv.z + xv.w*wdv.w;
    #pragma unroll
    for (int o = 32; o > 0; o >>= 1) {
        ps += __shfl_down(ps, o);
        pd += __shfl_down(pd, o);
    }
    if (lane == 0) { a_s[wave] = ps; a_d[wave] = pd; }
}

__device__ __forceinline__ float lrelu_exp(float e) {
    e = (e > 0.f) ? e : NEG_SLOPE * e;
    return __expf(e);
}

// Pass 1: ex -> d_out (coalesced), per-block LDS segment sums -> partials.
// Software-pipelined: batches of 2 k-iterations, next batch's index loads
// issued before processing the current batch.
__global__ __launch_bounds__(EK_TPB) void k3_denom(
        const int* __restrict__ ei1, const int* __restrict__ ei2,
        const float* __restrict__ a_s, const float* __restrict__ a_d,
        float* __restrict__ partials, float* __restrict__ out,
        int E1, int g1_blocks) {
    __shared__ float ssum[NNODES];           // 16 KB
    __shared__ float las[NNODES];            // 16 KB  (32 KB total)
    int t = threadIdx.x;
    int b = blockIdx.x;
    const int* sp; int qbase, nodeoff, outq;
    if (b < g1_blocks) { sp = ei1; qbase = b * EK_QPB; nodeoff = 0; outq = qbase; }
    else { sp = ei2; qbase = (b - g1_blocks) * EK_QPB; nodeoff = NNODES; outq = E1/4 + qbase; }
    const int4* s4 = (const int4*)sp;
    const int4* d4 = (const int4*)(sp + E1);
    const float* adg = a_d + nodeoff;        // a_d gather via L1 (TA pipe)

    ((float4*)las)[t]  = ((const float4*)(a_s + nodeoff))[t];
    ((float4*)ssum)[t] = make_float4(0.f, 0.f, 0.f, 0.f);
    __syncthreads();

    float4* out4 = (float4*)out;

    // A/B register batches: buf[parity][i], i in {0,1} -> iteration 2*bt+i
    int4 sbuf[2][2], dbuf[2][2];
    #pragma unroll
    for (int i = 0; i < 2; ++i) {
        int q = qbase + (i << 10) + t;
        sbuf[0][i] = s4[q]; dbuf[0][i] = d4[q];
    }
    #pragma unroll
    for (int bt = 0; bt < 4; ++bt) {
        int cur = bt & 1, nxt = cur ^ 1;
        if (bt < 3) {
            #pragma unroll
            for (int i = 0; i < 2; ++i) {
                int q = qbase + (((bt + 1) * 2 + i) << 10) + t;
                sbuf[nxt][i] = s4[q]; dbuf[nxt][i] = d4[q];
            }
        }
        #pragma unroll
        for (int i = 0; i < 2; ++i) {
            int k = bt * 2 + i;
            int4 sv = sbuf[cur][i];
            int4 dv = dbuf[cur][i];
            float ad0 = adg[dv.x], ad1 = adg[dv.y], ad2 = adg[dv.z], ad3 = adg[dv.w];
            float e0 = lrelu_exp(las[sv.x] + ad0);
            float e1 = lrelu_exp(las[sv.y] + ad1);
            float e2 = lrelu_exp(las[sv.z] + ad2);
            float e3 = lrelu_exp(las[sv.w] + ad3);
            atomicAdd(&ssum[dv.x], e0);
            atomicAdd(&ssum[dv.y], e1);
            atomicAdd(&ssum[dv.z], e2);
            atomicAdd(&ssum[dv.w], e3);
            out4[outq + (k << 10) + t] = make_float4(e0, e1, e2, e3);
        }
    }
    __syncthreads();
    float* pb = partials + (size_t)b * NNODES;
    ((float4*)pb)[t] = ((float4*)ssum)[t];
}

__global__ void k4a_reduce(const float* __restrict__ partials,
                           float* __restrict__ partials2, int g1_blocks) {
    int tid = blockIdx.x * blockDim.x + threadIdx.x;
    int c  = tid >> 13;
    int sg = tid & (NSEG - 1);
    int bpc = g1_blocks >> 3;
    int b0 = ((sg < NNODES) ? 0 : g1_blocks) + c * bpc;
    int col = sg & (NNODES - 1);
    float s = 0.f;
    for (int j = 0; j < bpc; ++j)
        s += partials[(size_t)(b0 + j) * NNODES + col];
    partials2[tid] = s;
}

__global__ void k4b_inv(const float* __restrict__ partials2,
                        float* __restrict__ inv_denom) {
    int sg = blockIdx.x * blockDim.x + threadIdx.x;
    float s = 0.f;
    #pragma unroll
    for (int c = 0; c < 8; ++c) s += partials2[c * NSEG + sg];
    inv_denom[sg] = 1.0f / s;
}

// Pass 2: alpha = ex * inv_denom[dst], in-place on d_out. Pipelined A/B.
__global__ __launch_bounds__(EK_TPB) void k5_alpha(
        const int* __restrict__ ei1, const int* __restrict__ ei2,
        const float* __restrict__ inv_denom,
        float* __restrict__ out, int E1, int g1_blocks) {
    __shared__ float linv[NNODES];           // 16 KB
    int t = threadIdx.x;
    int b = blockIdx.x;
    const int* sp; int qbase, nodeoff, outq;
    if (b < g1_blocks) { sp = ei1; qbase = b * EK_QPB; nodeoff = 0; outq = qbase; }
    else { sp = ei2; qbase = (b - g1_blocks) * EK_QPB; nodeoff = NNODES; outq = E1/4 + qbase; }
    const int4* d4 = (const int4*)(sp + E1);

    ((float4*)linv)[t] = ((const float4*)(inv_denom + nodeoff))[t];
    __syncthreads();

    float4* out4 = (float4*)out;
    int4   dbuf[2][2];
    float4 ebuf[2][2];
    #pragma unroll
    for (int i = 0; i < 2; ++i) {
        int q = qbase + (i << 10) + t;
        dbuf[0][i] = d4[q];
        ebuf[0][i] = out4[outq + (i << 10) + t];
    }
    #pragma unroll
    for (int bt = 0; bt < 4; ++bt) {
        int cur = bt & 1, nxt = cur ^ 1;
        if (bt < 3) {
            #pragma unroll
            for (int i = 0; i < 2; ++i) {
                int k = (bt + 1) * 2 + i;
                int q = qbase + (k << 10) + t;
                dbuf[nxt][i] = d4[q];
                ebuf[nxt][i] = out4[outq + (k << 10) + t];
            }
        }
        #pragma unroll
        for (int i = 0; i < 2; ++i) {
            int k = bt * 2 + i;
            int4  dv = dbuf[cur][i];
            float4 ex = ebuf[cur][i];
            ex.x *= linv[dv.x];
            ex.y *= linv[dv.y];
            ex.z *= linv[dv.z];
            ex.w *= linv[dv.w];
            out4[outq + (k << 10) + t] = ex;
        }
    }
}

extern "C" void kernel_launch(void* const* d_in, const int* in_sizes, int n_in,
                              void* d_out, int out_size, void* d_ws, size_t ws_size,
                              hipStream_t stream) {
    const float* x1      = (const float*)d_in[0];
    const float* x2      = (const float*)d_in[1];
    const int*   ei1     = (const int*)d_in[2];
    const int*   ei2     = (const int*)d_in[3];
    const float* W       = (const float*)d_in[4];
    const float* att_src = (const float*)d_in[5];
    const float* att_dst = (const float*)d_in[6];
    float* out = (float*)d_out;

    const int E1 = in_sizes[2] / 2;          // 8388608 edges per graph

    float* wsf       = (float*)d_ws;
    float* wvs       = wsf;                  // 256
    float* wvd       = wsf + 256;            // 256
    float* a_s       = wsf + 512;            // 8192
    float* a_d       = wsf + 512 + NSEG;     // 8192
    float* inv_denom = wsf + 512 + 2*NSEG;   // 8192
    float* partials2 = wsf + 32768;          // 65536
    float* partials  = wsf + 131072;         // 512*4096 floats (8 MB)

    hipLaunchKernelGGL(k1_wvec, dim3(1), dim3(256), 0, stream,
                       W, att_src, att_dst, wvs, wvd);
    hipLaunchKernelGGL(k2_logits, dim3(2 * NNODES / 4), dim3(256), 0, stream,
                       x1, x2, wvs, wvd, a_s, a_d);

    int g1b = (E1 / 4) / EK_QPB;             // 256 blocks per graph half
    hipLaunchKernelGGL(k3_denom, dim3(2 * g1b), dim3(EK_TPB), 0, stream,
                       ei1, ei2, a_s, a_d, partials, out, E1, g1b);
    hipLaunchKernelGGL(k4a_reduce, dim3(8 * NSEG / 256), dim3(256), 0, stream,
                       partials, partials2, g1b);
    hipLaunchKernelGGL(k4b_inv, dim3(NSEG / 256), dim3(256), 0, stream,
                       partials2, inv_denom);
    hipLaunchKernelGGL(k5_alpha, dim3(2 * g1b), dim3(EK_TPB), 0, stream,
                       ei1, ei2, inv_denom, out, E1, g1b);
}